// Round 14
// baseline (12014.188 us; speedup 1.0000x reference)
//
#include <hip/hip_runtime.h>
#include <math.h>

#define NB 64
#define NT 512
#define ND 512
#define NH 256
#define NG 1024   // 4*H
#define NK 32
#define NBT (NB*NT)
#define NBAT 4    // batches per lstm block

__device__ __forceinline__ float sigf(float x) { return 1.f / (1.f + expf(-x)); }
__device__ __forceinline__ float hsum4(float4 v) { return v.x + v.y + v.z + v.w; }

// ---------------------------------------------------------------------------
// Weight prep (round-8 layout):
// ww[(((dir*4+s)*32 + g*8+j)*512 + tid)*4 + e] = Whh_dir[g*256+s*64+u][part*32+j*4+e]
// ---------------------------------------------------------------------------
__global__ void k_wprep3(const float* __restrict__ Wf, const float* __restrict__ Wb,
                         float* __restrict__ ww) {
    int f = blockIdx.x * 256 + threadIdx.x;      // 0 .. 524287
    int e   = f & 3;
    int tid = (f >> 2) & 511;
    int gj  = (f >> 11) & 31;
    int s   = (f >> 16) & 3;
    int dir = (f >> 18) & 1;
    int u = tid & 63, part = tid >> 6;
    int g = gj >> 3, j = gj & 7;
    const float* W = dir ? Wb : Wf;
    int row = g * 256 + s * 64 + u;
    int col = part * 32 + j * 4 + e;
    ww[f] = W[row * 256 + col];
}

// ---------------------------------------------------------------------------
// Input projection GEMM v3: 128x128 tile, 8x8/thread, BK=16 chunks with
// DOUBLE-BUFFERED LDS -> one barrier per chunk (32 vs r8's 64).
// Register profile identical to r8's k_gemm_f (loads die into ds_writes
// immediately; no cross-compute liveness -> no spill risk).
// Ascending-k summation: bit-identical logits to r8.
// ---------------------------------------------------------------------------
__global__ __launch_bounds__(256, 4)
void k_gemm3(const float* __restrict__ x, const float* __restrict__ Wf,
             const float* __restrict__ Wb, const float* __restrict__ bf,
             const float* __restrict__ bb, float* __restrict__ xpF,
             float* __restrict__ xpB, int bxBase) {
    __shared__ float As[2][16][132];
    __shared__ float Bs[2][16][132];
    int tid = threadIdx.x;
    int bx = blockIdx.x + bxBase;
    int dir = bx >> 3;
    const float* W    = dir ? Wb : Wf;
    const float* bias = dir ? bb : bf;
    float* xp         = dir ? xpB : xpF;
    int r0 = blockIdx.y << 7;
    int g0 = (bx & 7) << 7;
    int rl = tid >> 1, k8 = (tid & 1) << 3;
    const float* xa = x + (size_t)(r0 + rl) * ND + k8;
    const float* wa = W + (size_t)(g0 + rl) * ND + k8;
    int tx = tid & 15, ty = tid >> 4;

    {   // stage chunk 0 into buffer 0
        float4 a0 = *(const float4*)(xa);
        float4 a1 = *(const float4*)(xa + 4);
        float4 w0 = *(const float4*)(wa);
        float4 w1 = *(const float4*)(wa + 4);
        As[0][k8+0][rl]=a0.x; As[0][k8+1][rl]=a0.y; As[0][k8+2][rl]=a0.z; As[0][k8+3][rl]=a0.w;
        As[0][k8+4][rl]=a1.x; As[0][k8+5][rl]=a1.y; As[0][k8+6][rl]=a1.z; As[0][k8+7][rl]=a1.w;
        Bs[0][k8+0][rl]=w0.x; Bs[0][k8+1][rl]=w0.y; Bs[0][k8+2][rl]=w0.z; Bs[0][k8+3][rl]=w0.w;
        Bs[0][k8+4][rl]=w1.x; Bs[0][k8+5][rl]=w1.y; Bs[0][k8+6][rl]=w1.z; Bs[0][k8+7][rl]=w1.w;
    }
    __syncthreads();

    float acc[8][8] = {};
    #pragma unroll 2
    for (int c = 0; c < 32; ++c) {
        int cur = c & 1;
        if (c < 31) {   // stage chunk c+1 into the other buffer (no barrier
                        // needed: peers read buf cur, we write buf cur^1)
            const float* xn = xa + (c + 1) * 16;
            const float* wn = wa + (c + 1) * 16;
            float4 a0 = *(const float4*)(xn);
            float4 a1 = *(const float4*)(xn + 4);
            float4 w0 = *(const float4*)(wn);
            float4 w1 = *(const float4*)(wn + 4);
            int nb = cur ^ 1;
            As[nb][k8+0][rl]=a0.x; As[nb][k8+1][rl]=a0.y; As[nb][k8+2][rl]=a0.z; As[nb][k8+3][rl]=a0.w;
            As[nb][k8+4][rl]=a1.x; As[nb][k8+5][rl]=a1.y; As[nb][k8+6][rl]=a1.z; As[nb][k8+7][rl]=a1.w;
            Bs[nb][k8+0][rl]=w0.x; Bs[nb][k8+1][rl]=w0.y; Bs[nb][k8+2][rl]=w0.z; Bs[nb][k8+3][rl]=w0.w;
            Bs[nb][k8+4][rl]=w1.x; Bs[nb][k8+5][rl]=w1.y; Bs[nb][k8+6][rl]=w1.z; Bs[nb][k8+7][rl]=w1.w;
        }
        #pragma unroll
        for (int kk = 0; kk < 16; ++kk) {
            float4 av0 = *(const float4*)(&As[cur][kk][ty << 3]);
            float4 av1 = *(const float4*)(&As[cur][kk][(ty << 3) + 4]);
            float4 bv0 = *(const float4*)(&Bs[cur][kk][tx << 3]);
            float4 bv1 = *(const float4*)(&Bs[cur][kk][(tx << 3) + 4]);
            float aa[8] = {av0.x, av0.y, av0.z, av0.w, av1.x, av1.y, av1.z, av1.w};
            float bbv[8] = {bv0.x, bv0.y, bv0.z, bv0.w, bv1.x, bv1.y, bv1.z, bv1.w};
            #pragma unroll
            for (int i = 0; i < 8; ++i)
                #pragma unroll
                for (int j = 0; j < 8; ++j)
                    acc[i][j] += aa[i] * bbv[j];
        }
        __syncthreads();   // buf cur reads done; buf cur^1 writes visible
    }
    float bv[8];
    #pragma unroll
    for (int j = 0; j < 8; ++j) bv[j] = bias[g0 + (tx << 3) + j];
    #pragma unroll
    for (int i = 0; i < 8; ++i) {
        float* orow = xp + (size_t)(r0 + (ty << 3) + i) * NG + g0 + (tx << 3);
        float4 o0 = {acc[i][0]+bv[0], acc[i][1]+bv[1], acc[i][2]+bv[2], acc[i][3]+bv[3]};
        float4 o1 = {acc[i][4]+bv[4], acc[i][5]+bv[5], acc[i][6]+bv[6], acc[i][7]+bv[7]};
        *(float4*)orow = o0;
        *(float4*)(orow + 4) = o1;
    }
}

// ---------------------------------------------------------------------------
// lstm macros (round-8)
// ---------------------------------------------------------------------------
#define FMA4(A, W, H) { (A).x += (W).x*(H).x; (A).y += (W).y*(H).y; \
                        (A).z += (W).z*(H).z; (A).w += (W).w*(H).w; }

#define DECLR(g) \
    float4 wr##g##_0 = wwp[qb + ((g)*8+0)*512]; \
    float4 wr##g##_1 = wwp[qb + ((g)*8+1)*512]; \
    float4 wr##g##_2 = wwp[qb + ((g)*8+2)*512]; \
    float4 wr##g##_3 = wwp[qb + ((g)*8+3)*512]; \
    float4 wr##g##_4 = wwp[qb + ((g)*8+4)*512];

#define DOTRJ(j) { float4 h_ = *(const float4*)(hb + (j)*4); \
    FMA4(a0, wr0_##j, h_) FMA4(a1, wr1_##j, h_) \
    FMA4(a2, wr2_##j, h_) FMA4(a3, wr3_##j, h_) }

#define DOTLJ(jj, j) { float4 h_ = *(const float4*)(hb + (j)*4); \
    { float4 l_ = lds_w[(0*3+(jj))*512 + tid]; FMA4(a0, l_, h_) } \
    { float4 l_ = lds_w[(1*3+(jj))*512 + tid]; FMA4(a1, l_, h_) } \
    { float4 l_ = lds_w[(2*3+(jj))*512 + tid]; FMA4(a2, l_, h_) } \
    { float4 l_ = lds_w[(3*3+(jj))*512 + tid]; FMA4(a3, l_, h_) } }

#define DOTALL DOTRJ(0) DOTRJ(1) DOTRJ(2) DOTRJ(3) DOTRJ(4) \
               DOTLJ(0,5) DOTLJ(1,6) DOTLJ(2,7)

// ---------------------------------------------------------------------------
// LSTM recurrence — round-8 k_lstm4 VERBATIM (best measured: 2050 us).
// ---------------------------------------------------------------------------
__global__ void
__attribute__((amdgpu_flat_work_group_size(512, 512)))
k_lstm4(const float* __restrict__ xpF, const float* __restrict__ xpB,
        const float* __restrict__ ww, const int* __restrict__ lengths,
        float* hsF, float* hsB, int hstr, int* flags, int gBase) {
    int bi = blockIdx.x;
    int g   = (bi & 7) + 8 * (bi >> 5) + gBase;
    int s   = (bi >> 3) & 3;
    int dir = g >> 4;
    int b0  = (g & 15) * NBAT;
    const float* xp = dir ? xpB : xpF;
    float* hsD      = dir ? hsB : hsF;

    int tid = threadIdx.x;
    int u  = tid & 63;
    int wv = tid >> 6;

    __shared__ float4 lds_w[12 * 512];
    __shared__ __align__(16) float hfull[NBAT][256];
    __shared__ float4 lds_part[NBAT][8][64];
    __shared__ int len4[NBAT];

    const float4* wwp = (const float4*)ww;
    int qb = ((dir * 4 + s) * 32) * 512 + tid;

    DECLR(0) DECLR(1) DECLR(2) DECLR(3)
    #pragma unroll
    for (int gg = 0; gg < 4; ++gg)
        #pragma unroll
        for (int jj = 0; jj < 3; ++jj)
            lds_w[(gg * 3 + jj) * 512 + tid] = wwp[qb + (gg * 8 + 5 + jj) * 512];

    if (tid < NBAT) len4[tid] = lengths[b0 + tid];
    ((float*)hfull)[tid] = 0.f;
    ((float*)hfull)[tid + 512] = 0.f;
    float c_state = 0.f;
    __syncthreads();

    int sb   = tid / 96;
    int sr   = tid - sb * 96;
    int spsi = sr >> 5, sq = sr & 31;
    int ssl  = spsi + (spsi >= s);
    unsigned long long* sdst =
        (unsigned long long*)&hfull[sb & 3][ssl * 64 + sq * 2];
    const float* ssrc0 = hsD + (size_t)(b0 + (sb & 3)) * NT * hstr + ssl * 64 + sq * 2;

    int pb = tid & 3, ps = tid >> 2;
    const int* pollp = flags + ((((dir << 6) + b0 + pb) << 2) + ps) * 512;

    float* hwp = hsD + (size_t)(b0 + wv) * NT * hstr + (s << 6) + u;
    int* flrelW0 = flags + ((((dir << 6) + b0 + u) << 2) + s) * 512;

    for (int tt = 0; tt < NT; ++tt) {
        int t = dir ? (NT - 1 - tt) : tt;

        float x0 = 0.f, x1 = 0.f, x2 = 0.f, x3 = 0.f;
        if (wv < NBAT) {
            const float* xr = xp + ((size_t)(b0 + wv) * NT + t) * NG + (s << 6) + u;
            x0 = xr[0]; x1 = xr[256]; x2 = xr[512]; x3 = xr[768];
        }
        if (tt > 0 && tid < 16 && ps != s && t < len4[pb]) {
            const int* fp = pollp + (tt - 1);
            while (__hip_atomic_load(fp, __ATOMIC_RELAXED,
                                     __HIP_MEMORY_SCOPE_AGENT) == 0) {}
        }
        __syncthreads();

        if (tt > 0 && tid < 384 && t < len4[sb]) {
            int t_prev = dir ? (t + 1) : (t - 1);
            unsigned long long v = __hip_atomic_load(
                (const unsigned long long*)(ssrc0 + (size_t)t_prev * hstr),
                __ATOMIC_RELAXED, __HIP_MEMORY_SCOPE_AGENT);
            *sdst = v;
        }
        __syncthreads();

        #pragma unroll
        for (int b = 0; b < NBAT; ++b) {
            if (tt > 0 && t < len4[b]) {
                const float* hb = &hfull[b][wv << 5];
                float4 a0 = {0.f,0.f,0.f,0.f}, a1 = a0, a2 = a0, a3 = a0;
                DOTALL
                lds_part[b][wv][u] = make_float4(hsum4(a0), hsum4(a1),
                                                 hsum4(a2), hsum4(a3));
            }
        }
        __syncthreads();

        if (wv < NBAT) {
            bool act = t < len4[wv];
            float pi, pf, pg, po;
            if (tt > 0 && act) {
                float4 q0 = lds_part[wv][0][u], q1 = lds_part[wv][1][u];
                float4 q2 = lds_part[wv][2][u], q3 = lds_part[wv][3][u];
                float4 q4 = lds_part[wv][4][u], q5 = lds_part[wv][5][u];
                float4 q6 = lds_part[wv][6][u], q7 = lds_part[wv][7][u];
                pi = q0.x+q1.x+q2.x+q3.x+q4.x+q5.x+q6.x+q7.x + x0;
                pf = q0.y+q1.y+q2.y+q3.y+q4.y+q5.y+q6.y+q7.y + x1;
                pg = q0.z+q1.z+q2.z+q3.z+q4.z+q5.z+q6.z+q7.z + x2;
                po = q0.w+q1.w+q2.w+q3.w+q4.w+q5.w+q6.w+q7.w + x3;
            } else {
                pi = x0; pf = x1; pg = x2; po = x3;
            }
            float h_old = hfull[wv][(s << 6) + u];
            float hv = h_old;
            if (act) {
                float gi = sigf(pi), gf = sigf(pf), gg = tanhf(pg), go = sigf(po);
                c_state = gf * c_state + gi * gg;
                hv = go * tanhf(c_state);
            }
            hfull[wv][(s << 6) + u] = hv;
            __hip_atomic_store(hwp + (size_t)t * hstr, hv,
                               __ATOMIC_RELAXED, __HIP_MEMORY_SCOPE_AGENT);
        }
        __syncthreads();

        if (wv == 0 && u < NBAT)
            __hip_atomic_store(flrelW0 + tt, 1, __ATOMIC_RELAXED,
                               __HIP_MEMORY_SCOPE_AGENT);
    }
}

// ---------------------------------------------------------------------------
// Classifier GEMM
// ---------------------------------------------------------------------------
__global__ __launch_bounds__(256, 4)
void k_clf(const float* __restrict__ hsF, const float* __restrict__ hsB,
           int hstr, const float* __restrict__ Wclf, const float* __restrict__ bclf,
           float* __restrict__ logits) {
    __shared__ float wt[512 * 32];
    __shared__ float xt[32 * 128];
    int tid = threadIdx.x;
    int r0 = blockIdx.x << 7;
    #pragma unroll
    for (int e = 0; e < 64; ++e) {
        int idx = e * 256 + tid;
        int kk = idx >> 9, j = idx & 511;
        wt[j * 32 + kk] = Wclf[idx];
    }
    int rl = tid >> 1, half = tid & 1;
    int kk = tid & 31, rg = tid >> 5;
    float acc[16] = {};
    for (int jc = 0; jc < 16; ++jc) {
        const float* src = (jc < 8 ? hsF : hsB) +
                           (size_t)(r0 + rl) * hstr + ((jc & 7) << 5) + (half << 4);
        float4 v0 = *(const float4*)(src + 0);
        float4 v1 = *(const float4*)(src + 4);
        float4 v2 = *(const float4*)(src + 8);
        float4 v3 = *(const float4*)(src + 12);
        __syncthreads();
        int jb = half << 4;
        xt[(jb+ 0)*128 + rl] = v0.x; xt[(jb+ 1)*128 + rl] = v0.y;
        xt[(jb+ 2)*128 + rl] = v0.z; xt[(jb+ 3)*128 + rl] = v0.w;
        xt[(jb+ 4)*128 + rl] = v1.x; xt[(jb+ 5)*128 + rl] = v1.y;
        xt[(jb+ 6)*128 + rl] = v1.z; xt[(jb+ 7)*128 + rl] = v1.w;
        xt[(jb+ 8)*128 + rl] = v2.x; xt[(jb+ 9)*128 + rl] = v2.y;
        xt[(jb+10)*128 + rl] = v2.z; xt[(jb+11)*128 + rl] = v2.w;
        xt[(jb+12)*128 + rl] = v3.x; xt[(jb+13)*128 + rl] = v3.y;
        xt[(jb+14)*128 + rl] = v3.z; xt[(jb+15)*128 + rl] = v3.w;
        __syncthreads();
        #pragma unroll
        for (int jp = 0; jp < 32; ++jp) {
            float w = wt[(jc * 32 + jp) * 32 + kk];
            const float* xr = &xt[jp * 128 + rg * 16];
            float4 x0 = *(const float4*)(xr + 0);
            float4 x1 = *(const float4*)(xr + 4);
            float4 x2 = *(const float4*)(xr + 8);
            float4 x3 = *(const float4*)(xr + 12);
            acc[ 0] += x0.x*w; acc[ 1] += x0.y*w; acc[ 2] += x0.z*w; acc[ 3] += x0.w*w;
            acc[ 4] += x1.x*w; acc[ 5] += x1.y*w; acc[ 6] += x1.z*w; acc[ 7] += x1.w*w;
            acc[ 8] += x2.x*w; acc[ 9] += x2.y*w; acc[10] += x2.z*w; acc[11] += x2.w*w;
            acc[12] += x3.x*w; acc[13] += x3.y*w; acc[14] += x3.z*w; acc[15] += x3.w*w;
        }
    }
    float bb = bclf[kk];
    #pragma unroll
    for (int i = 0; i < 16; ++i)
        logits[(size_t)(r0 + rg * 16 + i) * NK + kk] = acc[i] + bb;
}

// ---------------------------------------------------------------------------
// Viterbi: one wave per batch, ref-exact rounding order
// ---------------------------------------------------------------------------
__global__ __launch_bounds__(64)
void k_viterbi(const float* __restrict__ logits, const int* __restrict__ lengths,
               const float* __restrict__ st, const float* __restrict__ et,
               const float* __restrict__ trans, float* __restrict__ preds) {
    int b = blockIdx.x, lane = threadIdx.x;
    __shared__ unsigned char hist[NT - 1][NK];
    int len = lengths[b];
    int k = lane & 31;
    float wt[32];
    #pragma unroll
    for (int j = 0; j < 32; ++j) wt[j] = trans[j * NK + k];
    const float* lg = logits + (size_t)b * NT * NK;
    float score = st[k] + lg[k];
    for (int t = 1; t < NT; ++t) {
        float emis = lg[t * NK + k];
        float best = -3.4e38f; int bidx = 0;
        #pragma unroll
        for (int j = 0; j < 32; ++j) {
            float cand = (__shfl(score, j, 64) + wt[j]) + emis;
            if (cand > best) { best = cand; bidx = j; }
        }
        bool m = t < len;
        if (lane < 32) hist[t - 1][k] = (unsigned char)(m ? bidx : k);
        score = m ? best : score;
    }
    score += et[k];
    float bv = -3.4e38f; int btag = 0;
    #pragma unroll
    for (int j = 0; j < 32; ++j) {
        float v = __shfl(score, j, 64);
        if (v > bv) { bv = v; btag = j; }
    }
    __syncthreads();
    if (lane == 0) {
        int tag = btag;
        for (int t = NT - 1; t >= 1; --t) {
            preds[(size_t)b * NT + t] = (t < len) ? (float)tag : 0.f;
            tag = hist[t - 1][tag];
        }
        preds[(size_t)b * NT] = (float)tag;
    }
}

// ---------------------------------------------------------------------------
extern "C" void kernel_launch(void* const* d_in, const int* in_sizes, int n_in,
                              void* d_out, int out_size, void* d_ws, size_t ws_size,
                              hipStream_t stream) {
    (void)in_sizes; (void)n_in; (void)out_size;
    const float* x       = (const float*)d_in[0];
    const int*   lengths = (const int*)d_in[1];
    const float* Wih_f = (const float*)d_in[3];
    const float* Whh_f = (const float*)d_in[4];
    const float* b_f   = (const float*)d_in[5];
    const float* Wih_b = (const float*)d_in[6];
    const float* Whh_b = (const float*)d_in[7];
    const float* b_b   = (const float*)d_in[8];
    const float* W_clf = (const float*)d_in[9];
    const float* b_clf = (const float*)d_in[10];
    const float* st    = (const float*)d_in[11];
    const float* et    = (const float*)d_in[12];
    const float* trans = (const float*)d_in[13];

    float* logits = (float*)d_out;
    float* preds  = logits + (size_t)NBT * NK;

    // scratch inside the (not-yet-written) logits region of d_out (4 MB):
    // ww 2 MB @0; flags 1 MB @2MB. k_clf overwrites both later.
    float* wwp = logits;
    int*   flg = (int*)(logits + 524288);
    const size_t FLB = (size_t)262144 * 4;            // 2*64*4*512 ints

    const size_t XPB = (size_t)NBT * NG * 4;          // 134,217,728
    bool conc = ws_size >= 2 * XPB;

    char* ws = (char*)d_ws;
    float* xp0 = (float*)ws;
    float* xp1 = conc ? (float*)(ws + XPB) : xp0;
    float *hsF, *hsB; int hstr;
    if (conc) {
        hsF = xp0; hsB = xp1; hstr = NG;              // h aliases gate-i columns
    } else {
        hsF = (float*)(ws + XPB); hsB = hsF + (size_t)NB * NT * NH; hstr = NH;
    }

    hipMemsetAsync(flg, 0, FLB, stream);
    k_wprep3<<<2048, 256, 0, stream>>>(Whh_f, Whh_b, wwp);

    if (conc) {
        k_gemm3<<<dim3(16, 256), 256, 0, stream>>>(x, Wih_f, Wih_b, b_f, b_b,
                                                   xp0, xp1, 0);
        k_lstm4<<<128, 512, 0, stream>>>(xp0, xp1, wwp, lengths,
                                         hsF, hsB, hstr, flg, 0);
    } else {
        k_gemm3<<<dim3(8, 256), 256, 0, stream>>>(x, Wih_f, Wih_b, b_f, b_b,
                                                  xp0, xp0, 0);
        k_lstm4<<<64, 512, 0, stream>>>(xp0, xp0, wwp, lengths,
                                        hsF, hsB, hstr, flg, 0);
        k_gemm3<<<dim3(8, 256), 256, 0, stream>>>(x, Wih_f, Wih_b, b_f, b_b,
                                                  xp0, xp0, 8);
        k_lstm4<<<64, 512, 0, stream>>>(xp0, xp0, wwp, lengths,
                                        hsF, hsB, hstr, flg, 16);
    }
    k_clf<<<256, 256, 0, stream>>>(hsF, hsB, hstr, W_clf, b_clf, logits);
    k_viterbi<<<NB, 64, 0, stream>>>(logits, lengths, st, et, trans, preds);
}

// Round 15
// 2770.475 us; speedup vs baseline: 4.3365x; 4.3365x over previous
//
#include <hip/hip_runtime.h>
#include <math.h>

#define NB 64
#define NT 512
#define ND 512
#define NH 256
#define NG 1024   // 4*H
#define NK 32
#define NBT (NB*NT)

__device__ __forceinline__ float sigf(float x) { return 1.f / (1.f + expf(-x)); }
__device__ __forceinline__ float hsum4(float4 v) { return v.x + v.y + v.z + v.w; }

// ---------------------------------------------------------------------------
// Weight prep (round-8 layout):
// ww[(((dir*4+s)*32 + g*8+j)*512 + tid)*4 + e] = Whh_dir[g*256+s*64+u][part*32+j*4+e]
// ---------------------------------------------------------------------------
__global__ void k_wprep3(const float* __restrict__ Wf, const float* __restrict__ Wb,
                         float* __restrict__ ww) {
    int f = blockIdx.x * 256 + threadIdx.x;      // 0 .. 524287
    int e   = f & 3;
    int tid = (f >> 2) & 511;
    int gj  = (f >> 11) & 31;
    int s   = (f >> 16) & 3;
    int dir = (f >> 18) & 1;
    int u = tid & 63, part = tid >> 6;
    int g = gj >> 3, j = gj & 7;
    const float* W = dir ? Wb : Wf;
    int row = g * 256 + s * 64 + u;
    int col = part * 32 + j * 4 + e;
    ww[f] = W[row * 256 + col];
}

// ---------------------------------------------------------------------------
// Input projection GEMM — round-8 k_gemm_f VERBATIM (the only GEMM shape
// this toolchain compiles without spilling; do not touch).
// ---------------------------------------------------------------------------
__global__ __launch_bounds__(256, 4)
void k_gemm_f(const float* __restrict__ x, const float* __restrict__ Wf,
              const float* __restrict__ Wb, const float* __restrict__ bf,
              const float* __restrict__ bb, float* __restrict__ xpF,
              float* __restrict__ xpB, int bxBase) {
    __shared__ float As[16][132];
    __shared__ float Bs[16][132];
    int tid = threadIdx.x;
    int bx = blockIdx.x + bxBase;
    int dir = bx >> 3;
    const float* W    = dir ? Wb : Wf;
    const float* bias = dir ? bb : bf;
    float* xp         = dir ? xpB : xpF;
    int r0 = blockIdx.y << 7;
    int g0 = (bx & 7) << 7;
    int rl = tid >> 1, k8 = (tid & 1) << 3;
    const float* xa = x + (size_t)(r0 + rl) * ND + k8;
    const float* wa = W + (size_t)(g0 + rl) * ND + k8;
    int tx = tid & 15, ty = tid >> 4;
    float acc[8][8] = {};
    for (int kt = 0; kt < ND; kt += 16) {
        float4 a0 = *(const float4*)(xa + kt);
        float4 a1 = *(const float4*)(xa + kt + 4);
        float4 w0 = *(const float4*)(wa + kt);
        float4 w1 = *(const float4*)(wa + kt + 4);
        As[k8+0][rl]=a0.x; As[k8+1][rl]=a0.y; As[k8+2][rl]=a0.z; As[k8+3][rl]=a0.w;
        As[k8+4][rl]=a1.x; As[k8+5][rl]=a1.y; As[k8+6][rl]=a1.z; As[k8+7][rl]=a1.w;
        Bs[k8+0][rl]=w0.x; Bs[k8+1][rl]=w0.y; Bs[k8+2][rl]=w0.z; Bs[k8+3][rl]=w0.w;
        Bs[k8+4][rl]=w1.x; Bs[k8+5][rl]=w1.y; Bs[k8+6][rl]=w1.z; Bs[k8+7][rl]=w1.w;
        __syncthreads();
        #pragma unroll
        for (int kk = 0; kk < 16; ++kk) {
            float4 av0 = *(const float4*)(&As[kk][ty << 3]);
            float4 av1 = *(const float4*)(&As[kk][(ty << 3) + 4]);
            float4 bv0 = *(const float4*)(&Bs[kk][tx << 3]);
            float4 bv1 = *(const float4*)(&Bs[kk][(tx << 3) + 4]);
            float aa[8] = {av0.x, av0.y, av0.z, av0.w, av1.x, av1.y, av1.z, av1.w};
            float bbv[8] = {bv0.x, bv0.y, bv0.z, bv0.w, bv1.x, bv1.y, bv1.z, bv1.w};
            #pragma unroll
            for (int i = 0; i < 8; ++i)
                #pragma unroll
                for (int j = 0; j < 8; ++j)
                    acc[i][j] += aa[i] * bbv[j];
        }
        __syncthreads();
    }
    float bv[8];
    #pragma unroll
    for (int j = 0; j < 8; ++j) bv[j] = bias[g0 + (tx << 3) + j];
    #pragma unroll
    for (int i = 0; i < 8; ++i) {
        float* orow = xp + (size_t)(r0 + (ty << 3) + i) * NG + g0 + (tx << 3);
        float4 o0 = {acc[i][0]+bv[0], acc[i][1]+bv[1], acc[i][2]+bv[2], acc[i][3]+bv[3]};
        float4 o1 = {acc[i][4]+bv[4], acc[i][5]+bv[5], acc[i][6]+bv[6], acc[i][7]+bv[7]};
        *(float4*)orow = o0;
        *(float4*)(orow + 4) = o1;
    }
}

// ---------------------------------------------------------------------------
// lstm macros (round-8)
// ---------------------------------------------------------------------------
#define FMA4(A, W, H) { (A).x += (W).x*(H).x; (A).y += (W).y*(H).y; \
                        (A).z += (W).z*(H).z; (A).w += (W).w*(H).w; }

#define DECLR(g) \
    float4 wr##g##_0 = wwp[qb + ((g)*8+0)*512]; \
    float4 wr##g##_1 = wwp[qb + ((g)*8+1)*512]; \
    float4 wr##g##_2 = wwp[qb + ((g)*8+2)*512]; \
    float4 wr##g##_3 = wwp[qb + ((g)*8+3)*512]; \
    float4 wr##g##_4 = wwp[qb + ((g)*8+4)*512];

#define DOTRJ(j) { float4 h_ = *(const float4*)(hb + (j)*4); \
    FMA4(a0, wr0_##j, h_) FMA4(a1, wr1_##j, h_) \
    FMA4(a2, wr2_##j, h_) FMA4(a3, wr3_##j, h_) }

#define DOTLJ(jj, j) { float4 h_ = *(const float4*)(hb + (j)*4); \
    { float4 l_ = lds_w[(0*3+(jj))*512 + tid]; FMA4(a0, l_, h_) } \
    { float4 l_ = lds_w[(1*3+(jj))*512 + tid]; FMA4(a1, l_, h_) } \
    { float4 l_ = lds_w[(2*3+(jj))*512 + tid]; FMA4(a2, l_, h_) } \
    { float4 l_ = lds_w[(3*3+(jj))*512 + tid]; FMA4(a3, l_, h_) } }

#define DOTALL DOTRJ(0) DOTRJ(1) DOTRJ(2) DOTRJ(3) DOTRJ(4) \
               DOTLJ(0,5) DOTLJ(1,6) DOTLJ(2,7)

// ---------------------------------------------------------------------------
// LSTM recurrence — round-8 k_lstm4 structure with NBAT=2 (parameter change
// only): 256 blocks (1/CU), 2 batches per block, same weight split, same
// sync skeleton, same summation order (bit-identical h).
//  - staging threads 0..191 (2 batches x 96 ulongs)
//  - pollers threads 0..7 (2 batches x 4 slices, skip own)
//  - update waves 0..1
// ---------------------------------------------------------------------------
__global__ void
__attribute__((amdgpu_flat_work_group_size(512, 512)))
k_lstm4b(const float* __restrict__ xpF, const float* __restrict__ xpB,
         const float* __restrict__ ww, const int* __restrict__ lengths,
         float* hsF, float* hsB, int hstr, int* flags, int gBase) {
    int bi = blockIdx.x;
    int g   = (bi & 7) + 8 * (bi >> 5) + gBase;  // 0..63: dir*32 + group
    int s   = (bi >> 3) & 3;                     // u-slice; siblings share bi&7
    int dir = g >> 5;
    int b0  = (g & 31) * 2;
    const float* xp = dir ? xpB : xpF;
    float* hsD      = dir ? hsB : hsF;

    int tid = threadIdx.x;
    int u  = tid & 63;
    int wv = tid >> 6;                           // wave = v-chunk (part) 0..7

    __shared__ float4 lds_w[12 * 512];           // 96 KB
    __shared__ __align__(16) float hfull[2][256];
    __shared__ float4 lds_part[2][8][64];        // 16 KB
    __shared__ int len4[2];

    const float4* wwp = (const float4*)ww;
    int qb = ((dir * 4 + s) * 32) * 512 + tid;

    DECLR(0) DECLR(1) DECLR(2) DECLR(3)          // 20 named quads -> VGPRs
    #pragma unroll
    for (int gg = 0; gg < 4; ++gg)
        #pragma unroll
        for (int jj = 0; jj < 3; ++jj)
            lds_w[(gg * 3 + jj) * 512 + tid] = wwp[qb + (gg * 8 + 5 + jj) * 512];

    if (tid < 2) len4[tid] = lengths[b0 + tid];
    ((float*)hfull)[tid] = 0.f;                  // 512 floats exactly
    float c_state = 0.f;
    __syncthreads();

    // staging assignment (threads 0..191): 96 ulongs per batch
    int sb   = (tid < 192) ? (tid / 96) : 0;     // batch 0..1
    int sr   = tid - sb * 96;
    int spsi = (sr >> 5) & 3, sq = sr & 31;
    int ssl  = spsi + (spsi >= s);               // partner slice
    unsigned long long* sdst =
        (unsigned long long*)&hfull[sb & 1][ssl * 64 + sq * 2];
    const float* ssrc0 = hsD + (size_t)(b0 + (sb & 1)) * NT * hstr + ssl * 64 + sq * 2;

    // poller assignment (threads 0..7): (pb, ps)
    int pb = tid & 1, ps = (tid >> 1) & 3;
    const int* pollp = flags + ((((dir << 6) + b0 + pb) << 2) + ps) * 512;

    // update-wave global h pointer (waves 0..1)
    float* hwp = hsD + (size_t)(b0 + (wv & 1)) * NT * hstr + (s << 6) + u;
    // release flag pointer (wave 0 lanes 0..1: u = batch)
    int* flrelW0 = flags + ((((dir << 6) + b0 + (u & 1)) << 2) + s) * 512;

    for (int tt = 0; tt < NT; ++tt) {
        int t = dir ? (NT - 1 - tt) : tt;

        // A: xp prefetch (waves 0..1, batch wv's 4 gate columns)
        float x0 = 0.f, x1 = 0.f, x2 = 0.f, x3 = 0.f;
        if (wv < 2) {
            const float* xr = xp + ((size_t)(b0 + wv) * NT + t) * NG + (s << 6) + u;
            x0 = xr[0]; x1 = xr[256]; x2 = xr[512]; x3 = xr[768];
        }
        // B: poll partner flags RELAXED
        if (tt > 0 && tid < 8 && ps != s && t < len4[pb]) {
            const int* fp = pollp + (tt - 1);
            while (__hip_atomic_load(fp, __ATOMIC_RELAXED,
                                     __HIP_MEMORY_SCOPE_AGENT) == 0) {}
        }
        __syncthreads();   // C: flag loads complete block-wide

        // D: stage partner h via 64-bit relaxed atomic loads
        if (tt > 0 && tid < 192 && t < len4[sb]) {
            int t_prev = dir ? (t + 1) : (t - 1);
            unsigned long long v = __hip_atomic_load(
                (const unsigned long long*)(ssrc0 + (size_t)t_prev * hstr),
                __ATOMIC_RELAXED, __HIP_MEMORY_SCOPE_AGENT);
            *sdst = v;
        }
        __syncthreads();   // E

        // F: 2 dots (block-uniform skip per batch)
        #pragma unroll
        for (int b = 0; b < 2; ++b) {
            if (tt > 0 && t < len4[b]) {
                const float* hb = &hfull[b][wv << 5];
                float4 a0 = {0.f,0.f,0.f,0.f}, a1 = a0, a2 = a0, a3 = a0;
                DOTALL
                lds_part[b][wv][u] = make_float4(hsum4(a0), hsum4(a1),
                                                 hsum4(a2), hsum4(a3));
            }
        }
        __syncthreads();   // G

        // H: update (wave b owns batch b); publish h via relaxed atomic store
        if (wv < 2) {
            bool act = t < len4[wv];
            float pi, pf, pg, po;
            if (tt > 0 && act) {
                float4 q0 = lds_part[wv][0][u], q1 = lds_part[wv][1][u];
                float4 q2 = lds_part[wv][2][u], q3 = lds_part[wv][3][u];
                float4 q4 = lds_part[wv][4][u], q5 = lds_part[wv][5][u];
                float4 q6 = lds_part[wv][6][u], q7 = lds_part[wv][7][u];
                pi = q0.x+q1.x+q2.x+q3.x+q4.x+q5.x+q6.x+q7.x + x0;
                pf = q0.y+q1.y+q2.y+q3.y+q4.y+q5.y+q6.y+q7.y + x1;
                pg = q0.z+q1.z+q2.z+q3.z+q4.z+q5.z+q6.z+q7.z + x2;
                po = q0.w+q1.w+q2.w+q3.w+q4.w+q5.w+q6.w+q7.w + x3;
            } else {
                pi = x0; pf = x1; pg = x2; po = x3;
            }
            float h_old = hfull[wv][(s << 6) + u];
            float hv = h_old;
            if (act) {
                float gi = sigf(pi), gf = sigf(pf), gg = tanhf(pg), go = sigf(po);
                c_state = gf * c_state + gi * gg;
                hv = go * tanhf(c_state);
            }
            hfull[wv][(s << 6) + u] = hv;
            __hip_atomic_store(hwp + (size_t)t * hstr, hv,
                               __ATOMIC_RELAXED, __HIP_MEMORY_SCOPE_AGENT);
        }
        __syncthreads();   // I: all h atomic stores complete (vmcnt drain)

        // J: relaxed flag release (wave 0 lanes 0..1)
        if (wv == 0 && u < 2)
            __hip_atomic_store(flrelW0 + tt, 1, __ATOMIC_RELAXED,
                               __HIP_MEMORY_SCOPE_AGENT);
    }
}

// ---------------------------------------------------------------------------
// Classifier GEMM
// ---------------------------------------------------------------------------
__global__ __launch_bounds__(256, 4)
void k_clf(const float* __restrict__ hsF, const float* __restrict__ hsB,
           int hstr, const float* __restrict__ Wclf, const float* __restrict__ bclf,
           float* __restrict__ logits) {
    __shared__ float wt[512 * 32];
    __shared__ float xt[32 * 128];
    int tid = threadIdx.x;
    int r0 = blockIdx.x << 7;
    #pragma unroll
    for (int e = 0; e < 64; ++e) {
        int idx = e * 256 + tid;
        int kk = idx >> 9, j = idx & 511;
        wt[j * 32 + kk] = Wclf[idx];
    }
    int rl = tid >> 1, half = tid & 1;
    int kk = tid & 31, rg = tid >> 5;
    float acc[16] = {};
    for (int jc = 0; jc < 16; ++jc) {
        const float* src = (jc < 8 ? hsF : hsB) +
                           (size_t)(r0 + rl) * hstr + ((jc & 7) << 5) + (half << 4);
        float4 v0 = *(const float4*)(src + 0);
        float4 v1 = *(const float4*)(src + 4);
        float4 v2 = *(const float4*)(src + 8);
        float4 v3 = *(const float4*)(src + 12);
        __syncthreads();
        int jb = half << 4;
        xt[(jb+ 0)*128 + rl] = v0.x; xt[(jb+ 1)*128 + rl] = v0.y;
        xt[(jb+ 2)*128 + rl] = v0.z; xt[(jb+ 3)*128 + rl] = v0.w;
        xt[(jb+ 4)*128 + rl] = v1.x; xt[(jb+ 5)*128 + rl] = v1.y;
        xt[(jb+ 6)*128 + rl] = v1.z; xt[(jb+ 7)*128 + rl] = v1.w;
        xt[(jb+ 8)*128 + rl] = v2.x; xt[(jb+ 9)*128 + rl] = v2.y;
        xt[(jb+10)*128 + rl] = v2.z; xt[(jb+11)*128 + rl] = v2.w;
        xt[(jb+12)*128 + rl] = v3.x; xt[(jb+13)*128 + rl] = v3.y;
        xt[(jb+14)*128 + rl] = v3.z; xt[(jb+15)*128 + rl] = v3.w;
        __syncthreads();
        #pragma unroll
        for (int jp = 0; jp < 32; ++jp) {
            float w = wt[(jc * 32 + jp) * 32 + kk];
            const float* xr = &xt[jp * 128 + rg * 16];
            float4 x0 = *(const float4*)(xr + 0);
            float4 x1 = *(const float4*)(xr + 4);
            float4 x2 = *(const float4*)(xr + 8);
            float4 x3 = *(const float4*)(xr + 12);
            acc[ 0] += x0.x*w; acc[ 1] += x0.y*w; acc[ 2] += x0.z*w; acc[ 3] += x0.w*w;
            acc[ 4] += x1.x*w; acc[ 5] += x1.y*w; acc[ 6] += x1.z*w; acc[ 7] += x1.w*w;
            acc[ 8] += x2.x*w; acc[ 9] += x2.y*w; acc[10] += x2.z*w; acc[11] += x2.w*w;
            acc[12] += x3.x*w; acc[13] += x3.y*w; acc[14] += x3.z*w; acc[15] += x3.w*w;
        }
    }
    float bb = bclf[kk];
    #pragma unroll
    for (int i = 0; i < 16; ++i)
        logits[(size_t)(r0 + rg * 16 + i) * NK + kk] = acc[i] + bb;
}

// ---------------------------------------------------------------------------
// Viterbi: one wave per batch, ref-exact rounding order
// ---------------------------------------------------------------------------
__global__ __launch_bounds__(64)
void k_viterbi(const float* __restrict__ logits, const int* __restrict__ lengths,
               const float* __restrict__ st, const float* __restrict__ et,
               const float* __restrict__ trans, float* __restrict__ preds) {
    int b = blockIdx.x, lane = threadIdx.x;
    __shared__ unsigned char hist[NT - 1][NK];
    int len = lengths[b];
    int k = lane & 31;
    float wt[32];
    #pragma unroll
    for (int j = 0; j < 32; ++j) wt[j] = trans[j * NK + k];
    const float* lg = logits + (size_t)b * NT * NK;
    float score = st[k] + lg[k];
    for (int t = 1; t < NT; ++t) {
        float emis = lg[t * NK + k];
        float best = -3.4e38f; int bidx = 0;
        #pragma unroll
        for (int j = 0; j < 32; ++j) {
            float cand = (__shfl(score, j, 64) + wt[j]) + emis;
            if (cand > best) { best = cand; bidx = j; }
        }
        bool m = t < len;
        if (lane < 32) hist[t - 1][k] = (unsigned char)(m ? bidx : k);
        score = m ? best : score;
    }
    score += et[k];
    float bv = -3.4e38f; int btag = 0;
    #pragma unroll
    for (int j = 0; j < 32; ++j) {
        float v = __shfl(score, j, 64);
        if (v > bv) { bv = v; btag = j; }
    }
    __syncthreads();
    if (lane == 0) {
        int tag = btag;
        for (int t = NT - 1; t >= 1; --t) {
            preds[(size_t)b * NT + t] = (t < len) ? (float)tag : 0.f;
            tag = hist[t - 1][tag];
        }
        preds[(size_t)b * NT] = (float)tag;
    }
}

// ---------------------------------------------------------------------------
extern "C" void kernel_launch(void* const* d_in, const int* in_sizes, int n_in,
                              void* d_out, int out_size, void* d_ws, size_t ws_size,
                              hipStream_t stream) {
    (void)in_sizes; (void)n_in; (void)out_size;
    const float* x       = (const float*)d_in[0];
    const int*   lengths = (const int*)d_in[1];
    const float* Wih_f = (const float*)d_in[3];
    const float* Whh_f = (const float*)d_in[4];
    const float* b_f   = (const float*)d_in[5];
    const float* Wih_b = (const float*)d_in[6];
    const float* Whh_b = (const float*)d_in[7];
    const float* b_b   = (const float*)d_in[8];
    const float* W_clf = (const float*)d_in[9];
    const float* b_clf = (const float*)d_in[10];
    const float* st    = (const float*)d_in[11];
    const float* et    = (const float*)d_in[12];
    const float* trans = (const float*)d_in[13];

    float* logits = (float*)d_out;
    float* preds  = logits + (size_t)NBT * NK;

    // scratch inside the (not-yet-written) logits region of d_out (4 MB):
    // ww 2 MB @0; flags 1 MB @2MB. k_clf overwrites both later.
    float* wwp = logits;
    int*   flg = (int*)(logits + 524288);
    const size_t FLB = (size_t)262144 * 4;            // 2*64*4*512 ints

    const size_t XPB = (size_t)NBT * NG * 4;          // 134,217,728
    bool conc = ws_size >= 2 * XPB;

    char* ws = (char*)d_ws;
    float* xp0 = (float*)ws;
    float* xp1 = conc ? (float*)(ws + XPB) : xp0;
    float *hsF, *hsB; int hstr;
    if (conc) {
        hsF = xp0; hsB = xp1; hstr = NG;              // h aliases gate-i columns
    } else {
        hsF = (float*)(ws + XPB); hsB = hsF + (size_t)NB * NT * NH; hstr = NH;
    }

    hipMemsetAsync(flg, 0, FLB, stream);
    k_wprep3<<<2048, 256, 0, stream>>>(Whh_f, Whh_b, wwp);

    if (conc) {
        k_gemm_f<<<dim3(16, 256), 256, 0, stream>>>(x, Wih_f, Wih_b, b_f, b_b,
                                                    xp0, xp1, 0);
        k_lstm4b<<<256, 512, 0, stream>>>(xp0, xp1, wwp, lengths,
                                          hsF, hsB, hstr, flg, 0);
    } else {
        k_gemm_f<<<dim3(8, 256), 256, 0, stream>>>(x, Wih_f, Wih_b, b_f, b_b,
                                                   xp0, xp0, 0);
        k_lstm4b<<<128, 512, 0, stream>>>(xp0, xp0, wwp, lengths,
                                          hsF, hsB, hstr, flg, 0);
        k_gemm_f<<<dim3(8, 256), 256, 0, stream>>>(x, Wih_f, Wih_b, b_f, b_b,
                                                   xp0, xp0, 8);
        k_lstm4b<<<128, 512, 0, stream>>>(xp0, xp0, wwp, lengths,
                                          hsF, hsB, hstr, flg, 32);
    }
    k_clf<<<256, 256, 0, stream>>>(hsF, hsB, hstr, W_clf, b_clf, logits);
    k_viterbi<<<NB, 64, 0, stream>>>(logits, lengths, st, et, trans, preds);
}